// Round 1
// baseline (2477.487 us; speedup 1.0000x reference)
//
#include <hip/hip_runtime.h>

// Problem constants (from reference)
#define NB 4
#define NN 20000
#define NE 320000
#define ND 64
#define NR 64
#define NT 1000
#define NL 6
#define LN_EPS 1e-5f

// ---------------------------------------------------------------- utilities
__global__ void zero_f4(float4* __restrict__ p, int n4) {
    int i = blockIdx.x * blockDim.x + threadIdx.x;
    if (i < n4) p[i] = make_float4(0.f, 0.f, 0.f, 0.f);
}

// query[b,d] = relrep[b, r_index[b], d]   (256 threads)
__global__ void compute_query(const float* __restrict__ relrep,
                              const int* __restrict__ r_index,
                              float* __restrict__ query) {
    int tid = threadIdx.x;
    int b = tid >> 6, d = tid & 63;
    query[tid] = relrep[(b * NR + r_index[b]) * ND + d];
}

// buf[b, h_index[b], d] = query[b,d]  (buf pre-zeroed; one write per b)
__global__ void scatter_query(float* __restrict__ buf,
                              const float* __restrict__ query,
                              const int* __restrict__ h_index) {
    int tid = threadIdx.x;
    int b = tid >> 6, d = tid & 63;
    buf[(b * NN + h_index[b]) * ND + d] = query[tid];
}

// rel[b,r,:] = relu(relrep[b,r,:] @ w1 + b1) @ w2 + b2 ; one wave per (b,r)
__global__ void rel_mlp(const float* __restrict__ relrep,
                        const float* __restrict__ w1, const float* __restrict__ b1,
                        const float* __restrict__ w2, const float* __restrict__ b2,
                        float* __restrict__ rel) {
    __shared__ float sin[ND];
    __shared__ float shid[ND];
    int br = blockIdx.x;        // b*NR + r
    int j = threadIdx.x;        // 0..63
    sin[j] = relrep[br * ND + j];
    __syncthreads();
    float acc = b1[j];
    #pragma unroll 8
    for (int k = 0; k < ND; ++k) acc += sin[k] * w1[k * ND + j];
    shid[j] = fmaxf(acc, 0.f);
    __syncthreads();
    float out = b2[j];
    #pragma unroll 8
    for (int k = 0; k < ND; ++k) out += shid[k] * w2[k * ND + j];
    rel[br * ND + j] = out;
}

// msg = x[b,src,:] * rel[b,type,:] * w ; atomicAdd into agg[b,dst,:]
// one wave per edge (4 waves / block), lane = channel
__global__ void message_scatter(const float* __restrict__ x,
                                const float* __restrict__ rel,
                                const int* __restrict__ ei,
                                const int* __restrict__ et,
                                const float* __restrict__ ew,
                                float* __restrict__ agg) {
    int e = blockIdx.x * 4 + (threadIdx.x >> 6);
    int lane = threadIdx.x & 63;
    int s = ei[e];
    int dd = ei[NE + e];
    int t = et[e];
    float w = ew[e];
    #pragma unroll
    for (int b = 0; b < NB; ++b) {
        float v = x[(b * NN + s) * ND + lane] * rel[(b * NR + t) * ND + lane] * w;
        atomicAdd(&agg[(b * NN + dd) * ND + lane], v);
    }
}

// h = concat(x,agg) @ cw + cb ; LayerNorm ; relu ; + x   — one wave per (b,n)
__global__ void conv_ln(const float* __restrict__ x, const float* __restrict__ agg,
                        const float* __restrict__ cw, const float* __restrict__ cb,
                        const float* __restrict__ g, const float* __restrict__ bb,
                        float* __restrict__ xo) {
    int gid = blockIdx.x * 4 + (threadIdx.x >> 6);   // b*NN + n
    int lane = threadIdx.x & 63;
    float xv = x[gid * ND + lane];
    float av = agg[gid * ND + lane];
    float acc = cb[lane];
    #pragma unroll 8
    for (int k = 0; k < ND; ++k) acc += __shfl(xv, k) * cw[k * ND + lane];
    #pragma unroll 8
    for (int k = 0; k < ND; ++k) acc += __shfl(av, k) * cw[(ND + k) * ND + lane];
    float s = acc, s2 = acc * acc;
    #pragma unroll
    for (int o = 32; o > 0; o >>= 1) { s += __shfl_xor(s, o); s2 += __shfl_xor(s2, o); }
    float mu  = s  * (1.f / ND);
    float var = s2 * (1.f / ND) - mu * mu;
    float rs  = rsqrtf(var + LN_EPS);
    float hn  = (acc - mu) * rs * g[lane] + bb[lane];
    hn = fmaxf(hn, 0.f);
    xo[gid * ND + lane] = hn + xv;
}

// score[b,t] = relu(concat(x[b,ti,:],query[b,:]) @ W1 + b1) @ W2 + b2
// one wave per (b,t); each lane owns hidden dims {lane, lane+64}
__global__ void final_score(const float* __restrict__ x, const float* __restrict__ query,
                            const int* __restrict__ t_index,
                            const float* __restrict__ w1, const float* __restrict__ b1,
                            const float* __restrict__ w2, const float* __restrict__ b2,
                            float* __restrict__ out) {
    int gid = blockIdx.x * 4 + (threadIdx.x >> 6);   // b*NT + t
    int lane = threadIdx.x & 63;
    int b = gid / NT;
    int ti = t_index[gid];
    float xv = x[(b * NN + ti) * ND + lane];
    float qv = query[b * ND + lane];
    float a0 = b1[lane], a1 = b1[lane + 64];
    #pragma unroll 8
    for (int k = 0; k < ND; ++k) {
        float f = __shfl(xv, k);
        a0 += f * w1[k * 128 + lane];
        a1 += f * w1[k * 128 + lane + 64];
    }
    #pragma unroll 8
    for (int k = 0; k < ND; ++k) {
        float f = __shfl(qv, k);
        a0 += f * w1[(ND + k) * 128 + lane];
        a1 += f * w1[(ND + k) * 128 + lane + 64];
    }
    a0 = fmaxf(a0, 0.f);
    a1 = fmaxf(a1, 0.f);
    float p = a0 * w2[lane] + a1 * w2[lane + 64];
    #pragma unroll
    for (int o = 32; o > 0; o >>= 1) p += __shfl_xor(p, o);
    if (lane == 0) out[gid] = p + b2[0];
}

extern "C" void kernel_launch(void* const* d_in, const int* in_sizes, int n_in,
                              void* d_out, int out_size, void* d_ws, size_t ws_size,
                              hipStream_t stream) {
    const int*   edge_index  = (const int*)d_in[0];
    const int*   edge_type   = (const int*)d_in[1];
    const float* relrep      = (const float*)d_in[2];
    const int*   h_index     = (const int*)d_in[3];
    const int*   r_index     = (const int*)d_in[4];
    const int*   t_index     = (const int*)d_in[5];
    const float* edge_weight = (const float*)d_in[6];
    const float* rp_w1  = (const float*)d_in[7];
    const float* rp_b1  = (const float*)d_in[8];
    const float* rp_w2  = (const float*)d_in[9];
    const float* rp_b2  = (const float*)d_in[10];
    const float* conv_w = (const float*)d_in[11];
    const float* conv_b = (const float*)d_in[12];
    const float* ln_g   = (const float*)d_in[13];
    const float* ln_b   = (const float*)d_in[14];
    const float* mlp_w1 = (const float*)d_in[15];
    const float* mlp_b1 = (const float*)d_in[16];
    const float* mlp_w2 = (const float*)d_in[17];
    const float* mlp_b2 = (const float*)d_in[18];
    float* out = (float*)d_out;

    const int BND = NB * NN * ND;            // 5,120,000 floats
    float* ws    = (float*)d_ws;
    float* query = ws;                       // 256
    float* rel   = query + 256;              // B*R*D = 16384
    float* x0    = rel + NB * NR * ND;       // BND
    float* x1    = x0 + BND;                 // BND
    float* agg   = x1 + BND;                 // BND   (total ~61.5 MB)

    compute_query<<<1, 256, 0, stream>>>(relrep, r_index, query);
    zero_f4<<<BND / 4 / 256, 256, 0, stream>>>((float4*)x0, BND / 4);
    scatter_query<<<1, 256, 0, stream>>>(x0, query, h_index);

    float* xc = x0;
    float* xn = x1;
    for (int l = 0; l < NL; ++l) {
        rel_mlp<<<NB * NR, 64, 0, stream>>>(relrep,
                                            rp_w1 + l * ND * ND, rp_b1 + l * ND,
                                            rp_w2 + l * ND * ND, rp_b2 + l * ND, rel);
        zero_f4<<<BND / 4 / 256, 256, 0, stream>>>((float4*)agg, BND / 4);
        scatter_query<<<1, 256, 0, stream>>>(agg, query, h_index);
        message_scatter<<<NE / 4, 256, 0, stream>>>(xc, rel, edge_index, edge_type,
                                                    edge_weight, agg);
        conv_ln<<<NB * NN / 4, 256, 0, stream>>>(xc, agg,
                                                 conv_w + l * 2 * ND * ND, conv_b + l * ND,
                                                 ln_g + l * ND, ln_b + l * ND, xn);
        float* tmp = xc; xc = xn; xn = tmp;
    }
    final_score<<<NB * NT / 4, 256, 0, stream>>>(xc, query, t_index,
                                                 mlp_w1, mlp_b1, mlp_w2, mlp_b2, out);
}

// Round 2
// 1032.636 us; speedup vs baseline: 2.3992x; 2.3992x over previous
//
#include <hip/hip_runtime.h>

#define NB 4
#define NN 20000
#define NE 320000
#define ND 64
#define NR 64
#define NT 1000
#define NL 6
#define LN_EPS 1e-5f

// ---------------------------------------------------------------- utilities
__global__ void zero_f4(float4* __restrict__ p, int n4) {
    int i = blockIdx.x * blockDim.x + threadIdx.x;
    if (i < n4) p[i] = make_float4(0.f, 0.f, 0.f, 0.f);
}

__global__ void zero_i(int* __restrict__ p, int n) {
    int i = blockIdx.x * blockDim.x + threadIdx.x;
    if (i < n) p[i] = 0;
}

// query[b,d] = relrep[b, r_index[b], d]
__global__ void compute_query(const float* __restrict__ relrep,
                              const int* __restrict__ r_index,
                              float* __restrict__ query) {
    int tid = threadIdx.x;
    int b = tid >> 6, d = tid & 63;
    query[tid] = relrep[(b * NR + r_index[b]) * ND + d];
}

// buf[b, h_index[b], d] = query[b,d]  (buf pre-zeroed)
__global__ void scatter_query(float* __restrict__ buf,
                              const float* __restrict__ query,
                              const int* __restrict__ h_index) {
    int tid = threadIdx.x;
    int b = tid >> 6;
    buf[(b * NN + h_index[b]) * ND + (tid & 63)] = query[tid];
}

// ---------------------------------------------------------------- CSR build
__global__ void hist_dst(const int* __restrict__ ei, int* __restrict__ deg) {
    int e = blockIdx.x * blockDim.x + threadIdx.x;
    if (e < NE) atomicAdd(&deg[ei[NE + e]], 1);
}

// single-block exclusive scan over deg[NN] -> row_off[NN+1]; also seeds cursor
__global__ void scan_deg(const int* __restrict__ deg, int* __restrict__ row_off,
                         int* __restrict__ cursor) {
    __shared__ int tmp[1024];
    __shared__ int carry;
    if (threadIdx.x == 0) carry = 0;
    __syncthreads();
    for (int base = 0; base < NN; base += 1024) {
        int i = base + (int)threadIdx.x;
        int v = (i < NN) ? deg[i] : 0;
        tmp[threadIdx.x] = v;
        __syncthreads();
        for (int o = 1; o < 1024; o <<= 1) {
            int t = (threadIdx.x >= o) ? tmp[threadIdx.x - o] : 0;
            __syncthreads();
            tmp[threadIdx.x] += t;
            __syncthreads();
        }
        int excl = tmp[threadIdx.x] - v;
        if (i < NN) { row_off[i] = carry + excl; cursor[i] = carry + excl; }
        __syncthreads();
        if (threadIdx.x == 0) carry += tmp[1023];
        __syncthreads();
    }
    if (threadIdx.x == 0) row_off[NN] = carry;   // == NE
}

__global__ void scatter_edges(const int* __restrict__ ei, const int* __restrict__ et,
                              const float* __restrict__ ew, int* __restrict__ cursor,
                              int* __restrict__ src_s, int* __restrict__ et_s,
                              float* __restrict__ ew_s) {
    int e = blockIdx.x * blockDim.x + threadIdx.x;
    if (e >= NE) return;
    int d = ei[NE + e];
    int p = atomicAdd(&cursor[d], 1);
    src_s[p] = ei[e];
    et_s[p] = et[e];
    ew_s[p] = ew[e];
}

// rel[b,r,:] = relu(relrep[b,r,:] @ w1 + b1) @ w2 + b2 ; one wave per (b,r)
__global__ void rel_mlp(const float* __restrict__ relrep,
                        const float* __restrict__ w1, const float* __restrict__ b1,
                        const float* __restrict__ w2, const float* __restrict__ b2,
                        float* __restrict__ rel) {
    __shared__ float sin[ND];
    __shared__ float shid[ND];
    int br = blockIdx.x;
    int j = threadIdx.x;
    sin[j] = relrep[br * ND + j];
    __syncthreads();
    float acc = b1[j];
    #pragma unroll 8
    for (int k = 0; k < ND; ++k) acc += sin[k] * w1[k * ND + j];
    shid[j] = fmaxf(acc, 0.f);
    __syncthreads();
    float out = b2[j];
    #pragma unroll 8
    for (int k = 0; k < ND; ++k) out += shid[k] * w2[k * ND + j];
    rel[br * ND + j] = out;
}

// ------------------------------------------------ fused gather+conv+LN layer
// one wave per node n; handles all 4 batches; agg stays in registers.
__global__ void __launch_bounds__(256)
fused_layer(const float* __restrict__ x, const float* __restrict__ rel,
            const int* __restrict__ row_off, const int* __restrict__ src_s,
            const int* __restrict__ et_s, const float* __restrict__ ew_s,
            const float* __restrict__ query, const int* __restrict__ h_index,
            const float* __restrict__ cw, const float* __restrict__ cb,
            const float* __restrict__ g, const float* __restrict__ bb,
            float* __restrict__ xo) {
    int n = blockIdx.x * 4 + (threadIdx.x >> 6);
    int lane = threadIdx.x & 63;
    int beg = row_off[n], end = row_off[n + 1];

    float agg[NB] = {0.f, 0.f, 0.f, 0.f};
    for (int e0 = beg; e0 < end; e0 += 64) {
        int cnt = min(64, end - e0);
        int es = 0, etv = 0; float ewv = 0.f;
        if (lane < cnt) {
            es  = src_s[e0 + lane];
            etv = et_s[e0 + lane];
            ewv = ew_s[e0 + lane];
        }
        for (int j = 0; j < cnt; ++j) {
            int s   = __shfl(es, j);
            int t   = __shfl(etv, j);
            float w = __shfl(ewv, j);
            #pragma unroll
            for (int b = 0; b < NB; ++b)
                agg[b] += x[(b * NN + s) * ND + lane] * rel[(b * NR + t) * ND + lane] * w;
        }
    }
    // boundary self-loop
    #pragma unroll
    for (int b = 0; b < NB; ++b)
        if (n == h_index[b]) agg[b] += query[b * ND + lane];

    // conv: concat(x, agg) @ cw + cb, shared weight loads across batches
    float xv[NB], accs[NB];
    #pragma unroll
    for (int b = 0; b < NB; ++b) {
        xv[b] = x[(b * NN + n) * ND + lane];
        accs[b] = cb[lane];
    }
    for (int k = 0; k < ND; ++k) {
        float wk = cw[k * ND + lane];
        #pragma unroll
        for (int b = 0; b < NB; ++b) accs[b] += __shfl(xv[b], k) * wk;
    }
    for (int k = 0; k < ND; ++k) {
        float wk = cw[(ND + k) * ND + lane];
        #pragma unroll
        for (int b = 0; b < NB; ++b) accs[b] += __shfl(agg[b], k) * wk;
    }
    // LN + relu + residual
    float gl = g[lane], bl = bb[lane];
    #pragma unroll
    for (int b = 0; b < NB; ++b) {
        float acc = accs[b];
        float s = acc, s2 = acc * acc;
        #pragma unroll
        for (int o = 32; o > 0; o >>= 1) { s += __shfl_xor(s, o); s2 += __shfl_xor(s2, o); }
        float mu  = s * (1.f / ND);
        float var = s2 * (1.f / ND) - mu * mu;
        float hn  = (acc - mu) * rsqrtf(var + LN_EPS) * gl + bl;
        xo[(b * NN + n) * ND + lane] = fmaxf(hn, 0.f) + xv[b];
    }
}

// score[b,t] = relu(concat(x[b,ti,:],query[b,:]) @ W1 + b1) @ W2 + b2
__global__ void final_score(const float* __restrict__ x, const float* __restrict__ query,
                            const int* __restrict__ t_index,
                            const float* __restrict__ w1, const float* __restrict__ b1,
                            const float* __restrict__ w2, const float* __restrict__ b2,
                            float* __restrict__ out) {
    int gid = blockIdx.x * 4 + (threadIdx.x >> 6);
    int lane = threadIdx.x & 63;
    int b = gid / NT;
    int ti = t_index[gid];
    float xv = x[(b * NN + ti) * ND + lane];
    float qv = query[b * ND + lane];
    float a0 = b1[lane], a1 = b1[lane + 64];
    #pragma unroll 8
    for (int k = 0; k < ND; ++k) {
        float f = __shfl(xv, k);
        a0 += f * w1[k * 128 + lane];
        a1 += f * w1[k * 128 + lane + 64];
    }
    #pragma unroll 8
    for (int k = 0; k < ND; ++k) {
        float f = __shfl(qv, k);
        a0 += f * w1[(ND + k) * 128 + lane];
        a1 += f * w1[(ND + k) * 128 + lane + 64];
    }
    a0 = fmaxf(a0, 0.f);
    a1 = fmaxf(a1, 0.f);
    float p = a0 * w2[lane] + a1 * w2[lane + 64];
    #pragma unroll
    for (int o = 32; o > 0; o >>= 1) p += __shfl_xor(p, o);
    if (lane == 0) out[gid] = p + b2[0];
}

extern "C" void kernel_launch(void* const* d_in, const int* in_sizes, int n_in,
                              void* d_out, int out_size, void* d_ws, size_t ws_size,
                              hipStream_t stream) {
    const int*   edge_index  = (const int*)d_in[0];
    const int*   edge_type   = (const int*)d_in[1];
    const float* relrep      = (const float*)d_in[2];
    const int*   h_index     = (const int*)d_in[3];
    const int*   r_index     = (const int*)d_in[4];
    const int*   t_index     = (const int*)d_in[5];
    const float* edge_weight = (const float*)d_in[6];
    const float* rp_w1  = (const float*)d_in[7];
    const float* rp_b1  = (const float*)d_in[8];
    const float* rp_w2  = (const float*)d_in[9];
    const float* rp_b2  = (const float*)d_in[10];
    const float* conv_w = (const float*)d_in[11];
    const float* conv_b = (const float*)d_in[12];
    const float* ln_g   = (const float*)d_in[13];
    const float* ln_b   = (const float*)d_in[14];
    const float* mlp_w1 = (const float*)d_in[15];
    const float* mlp_b1 = (const float*)d_in[16];
    const float* mlp_w2 = (const float*)d_in[17];
    const float* mlp_b2 = (const float*)d_in[18];
    float* out = (float*)d_out;

    const int BND = NB * NN * ND;            // 5,120,000 floats
    float* ws    = (float*)d_ws;
    float* query = ws;                       // 256
    float* rel   = query + 256;              // 16384
    float* x0    = rel + NB * NR * ND;       // BND
    float* x1    = x0 + BND;                 // BND
    float* ew_s  = x1 + BND;                 // NE
    int*   src_s = (int*)(ew_s + NE);        // NE
    int*   et_s  = src_s + NE;               // NE
    int*   deg   = et_s + NE;                // NN
    int*   row_off = deg + NN;               // NN+1
    int*   cursor  = row_off + NN + 1;       // NN
    // total ≈ 45 MB

    // --- CSR build (once per call, reused across 6 layers) ---
    zero_i<<<(NN + 255) / 256, 256, 0, stream>>>(deg, NN);
    hist_dst<<<(NE + 255) / 256, 256, 0, stream>>>(edge_index, deg);
    scan_deg<<<1, 1024, 0, stream>>>(deg, row_off, cursor);
    scatter_edges<<<(NE + 255) / 256, 256, 0, stream>>>(edge_index, edge_type, edge_weight,
                                                        cursor, src_s, et_s, ew_s);

    // --- boundary / x0 ---
    compute_query<<<1, 256, 0, stream>>>(relrep, r_index, query);
    zero_f4<<<BND / 4 / 256, 256, 0, stream>>>((float4*)x0, BND / 4);
    scatter_query<<<1, 256, 0, stream>>>(x0, query, h_index);

    float* xc = x0;
    float* xn = x1;
    for (int l = 0; l < NL; ++l) {
        rel_mlp<<<NB * NR, 64, 0, stream>>>(relrep,
                                            rp_w1 + l * ND * ND, rp_b1 + l * ND,
                                            rp_w2 + l * ND * ND, rp_b2 + l * ND, rel);
        fused_layer<<<NN / 4, 256, 0, stream>>>(xc, rel, row_off, src_s, et_s, ew_s,
                                                query, h_index,
                                                conv_w + l * 2 * ND * ND, conv_b + l * ND,
                                                ln_g + l * ND, ln_b + l * ND, xn);
        float* tmp = xc; xc = xn; xn = tmp;
    }
    final_score<<<NB * NT / 4, 256, 0, stream>>>(xc, query, t_index,
                                                 mlp_w1, mlp_b1, mlp_w2, mlp_b2, out);
}